// Round 2
// baseline (1867.625 us; speedup 1.0000x reference)
//
#include <hip/hip_runtime.h>
#include <math.h>

// Problem constants
#define N_ROWS 32768      // B*H*W = 8*64*64
#define K_CODES 4096
#define D_DIM 256
#define HW 4096           // H*W
#define CHW 1048576       // C*H*W = 256*4096

// Main argmin-GEMM tiling
#define BM 128
#define BN 128
#define BK 32
#define ES_S 132          // Es LDS leading-dim pad (128+4): breaks store conflicts, keeps 16B align

// Output layout (float element offsets): loss(1) | quantized(8388608) | perplexity(1)
//                                        | encodings(32768*4096) | idx(32768)
#define OFF_LOSS  0
#define OFF_QUANT 1ULL
#define OFF_PERP  8388609ULL
#define OFF_ENC   8388610ULL
#define OFF_IDX   142606338ULL

// Workspace layout (float element offsets)
#define WS_RN   0         // 32768 row norms
#define WS_EN   32768     // 4096 code norms
#define WS_IDX  36864     // 32768 int indices
#define WS_CNT  69632     // 4096 uint counts
#define WS_LOSS 73728     // 1 double (byte offset 294912, 8B aligned)

// numpy pairwise_sum replica for 128 squared elements (8-accumulator unroll).
__device__ __forceinline__ float pairwise_sq_128(const float* __restrict__ p, int stride) {
  float r[8];
#pragma unroll
  for (int j = 0; j < 8; ++j) { float v = p[(size_t)j * stride]; r[j] = v * v; }
#pragma unroll
  for (int g = 1; g < 16; ++g) {
#pragma unroll
    for (int j = 0; j < 8; ++j) { float v = p[(size_t)(g * 8 + j) * stride]; r[j] += v * v; }
  }
  return ((r[0] + r[1]) + (r[2] + r[3])) + ((r[4] + r[5]) + (r[6] + r[7]));
}

// ||x||^2 per flattened row (row elements strided by HW in z's [B,C,H,W] layout).
__global__ void rownorm_k(const float* __restrict__ z, float* __restrict__ rn) {
  int row = blockIdx.x * 256 + threadIdx.x;
  const float* p = z + (size_t)(row >> 12) * CHW + (row & (HW - 1));
  float h0 = pairwise_sq_128(p, HW);
  float h1 = pairwise_sq_128(p + (size_t)128 * HW, HW);
  rn[row] = h0 + h1;
}

// ||e||^2 per codebook row (contiguous).
__global__ void enorm_k(const float* __restrict__ cb, float* __restrict__ en) {
  int k = blockIdx.x * 256 + threadIdx.x;
  const float* p = cb + (size_t)k * D_DIM;
  en[k] = pairwise_sq_128(p, 1) + pairwise_sq_128(p + 128, 1);
}

// Fused distance GEMM + running argmin. Block: 128 rows x all 4096 codes.
__global__ __launch_bounds__(256) void argmin_k(
    const float* __restrict__ z, const float* __restrict__ cb,
    const float* __restrict__ rn, const float* __restrict__ en,
    int* __restrict__ idxbuf, unsigned int* __restrict__ counts,
    float* __restrict__ out) {
  __shared__ union {
    struct { float Xs[BK * BM]; float Es[BK * ES_S]; } s;
    struct { float rv[BM * 16]; int ri[BM * 16]; } r;
  } sh;

  const int tid = threadIdx.x;
  const int tx = tid & 15;   // code group
  const int ty = tid >> 4;   // row group
  const int row_base = blockIdx.x * BM;
  const float* zb = z + (size_t)(row_base >> 12) * CHW + (row_base & (HW - 1));

  float rnv[8];
#pragma unroll
  for (int i = 0; i < 8; ++i) rnv[i] = rn[row_base + ty * 8 + i];

  float bestV[8];
  int bestI[8];
#pragma unroll
  for (int i = 0; i < 8; ++i) { bestV[i] = 3.4e38f; bestI[i] = 0; }

  for (int t0 = 0; t0 < K_CODES; t0 += BN) {
    float acc[8][8];
#pragma unroll
    for (int i = 0; i < 8; ++i) {
#pragma unroll
      for (int j = 0; j < 8; ++j) acc[i][j] = 0.0f;
    }

    for (int kb = 0; kb < D_DIM; kb += BK) {
      __syncthreads();
      // Stage X chunk [BK x BM], K-major; rows contiguous in global -> coalesced float4.
#pragma unroll
      for (int k = 0; k < 4; ++k) {
        int l4 = tid + k * 256;
        int cl = l4 >> 5;
        int ro = (l4 & 31) << 2;
        float4 v = *(const float4*)(zb + (size_t)(kb + cl) * HW + ro);
        *(float4*)&sh.s.Xs[cl * BM + ro] = v;
      }
      // Stage E chunk [BK x BN] transposed (codebook is code-major in global).
#pragma unroll
      for (int k = 0; k < 4; ++k) {
        int l4 = tid + k * 256;
        int kl = l4 >> 3;
        int cq = (l4 & 7) << 2;
        float4 v = *(const float4*)(cb + (size_t)(t0 + kl) * D_DIM + kb + cq);
        sh.s.Es[(cq + 0) * ES_S + kl] = v.x;
        sh.s.Es[(cq + 1) * ES_S + kl] = v.y;
        sh.s.Es[(cq + 2) * ES_S + kl] = v.z;
        sh.s.Es[(cq + 3) * ES_S + kl] = v.w;
      }
      __syncthreads();

#pragma unroll 4
      for (int c = 0; c < BK; ++c) {
        float4 xa = *(const float4*)&sh.s.Xs[c * BM + ty * 8];
        float4 xb = *(const float4*)&sh.s.Xs[c * BM + ty * 8 + 4];
        // split code columns: tx*4..tx*4+3 and 64+tx*4..64+tx*4+3 (2-way LDS banks = free)
        float4 ea = *(const float4*)&sh.s.Es[c * ES_S + tx * 4];
        float4 eb = *(const float4*)&sh.s.Es[c * ES_S + 64 + tx * 4];
        float xv[8] = {xa.x, xa.y, xa.z, xa.w, xb.x, xb.y, xb.z, xb.w};
        float ev[8] = {ea.x, ea.y, ea.z, ea.w, eb.x, eb.y, eb.z, eb.w};
#pragma unroll
        for (int i = 0; i < 8; ++i) {
#pragma unroll
          for (int j = 0; j < 8; ++j) acc[i][j] = fmaf(xv[i], ev[j], acc[i][j]);
        }
      }
    }

    // Scores for this code tile; replicate reference rounding:
    // d = fl( fl(rn + en) - fl(2*dot) ).  (2*dot is exact scaling.)
#pragma unroll
    for (int j = 0; j < 8; ++j) {
      int code = t0 + ((j < 4) ? (tx * 4 + j) : (64 + tx * 4 + (j - 4)));
      float ev = en[code];
#pragma unroll
      for (int i = 0; i < 8; ++i) {
        float d = (rnv[i] + ev) - 2.0f * acc[i][j];
        if (d < bestV[i]) { bestV[i] = d; bestI[i] = code; }  // strict <: first/lowest idx wins
      }
    }
  }

  // Cross-thread (tx) reduction per row, lexicographic (val, idx).
  __syncthreads();
#pragma unroll
  for (int i = 0; i < 8; ++i) {
    sh.r.rv[(ty * 8 + i) * 16 + tx] = bestV[i];
    sh.r.ri[(ty * 8 + i) * 16 + tx] = bestI[i];
  }
  __syncthreads();
  if (tid < BM) {
    float bv = sh.r.rv[tid * 16];
    int bi = sh.r.ri[tid * 16];
    for (int t = 1; t < 16; ++t) {
      float v = sh.r.rv[tid * 16 + t];
      int ii = sh.r.ri[tid * 16 + t];
      if (v < bv || (v == bv && ii < bi)) { bv = v; bi = ii; }
    }
    int row = row_base + tid;
    idxbuf[row] = bi;
    out[OFF_IDX + row] = (float)bi;
    out[OFF_ENC + (size_t)row * K_CODES + bi] = 1.0f;  // one-hot scatter (region pre-zeroed)
    atomicAdd(&counts[bi], 1u);
  }
}

// Gather codebook rows -> quantized_out (with STE rounding: z + (q - z)), accumulate loss sum.
__global__ void quant_k(const float* __restrict__ z, const float* __restrict__ cb,
                        const int* __restrict__ idxbuf, float* __restrict__ out,
                        double* __restrict__ losssum) {
  __shared__ double red[256];
  int bh = blockIdx.x;
  int b = bh >> 6, h = bh & 63;
  int tid = threadIdx.x;
  int w = tid & 63, c0 = tid >> 6;
  int n = (b << 12) + (h << 6) + w;
  int iv = idxbuf[n];
  const float* cbr = cb + (size_t)iv * D_DIM;
  size_t zoff = (size_t)b * CHW + (size_t)(h << 6) + w;
  double s = 0.0;
  for (int c = c0; c < D_DIM; c += 4) {
    float zv = z[zoff + (size_t)c * HW];
    float q = cbr[c];
    float diff = q - zv;                                  // fl(q - z)
    out[OFF_QUANT + zoff + (size_t)c * HW] = zv + diff;   // fl(z + fl(q - z)) : STE forward value
    double dd = (double)q - (double)zv;
    s += dd * dd;
  }
  red[tid] = s;
  __syncthreads();
  for (int st = 128; st > 0; st >>= 1) {
    if (tid < st) red[tid] += red[tid + st];
    __syncthreads();
  }
  if (tid == 0) atomicAdd(losssum, red[0]);
}

// Perplexity from histogram + final loss scalar.
__global__ void final_k(const unsigned int* __restrict__ counts,
                        const double* __restrict__ losssum, float* __restrict__ out) {
  __shared__ double red[256];
  int tid = threadIdx.x;
  double s = 0.0;
  for (int k = tid; k < K_CODES; k += 256) {
    double p = (double)counts[k] / 32768.0;
    s += p * log(p + 1e-10);
  }
  red[tid] = s;
  __syncthreads();
  for (int st = 128; st > 0; st >>= 1) {
    if (tid < st) red[tid] += red[tid + st];
    __syncthreads();
  }
  if (tid == 0) {
    out[OFF_PERP] = (float)exp(-red[0]);
    // loss = q_latent + 0.25*e_latent; both equal mean((q - z)^2) in forward value.
    out[OFF_LOSS] = (float)(1.25 * losssum[0] / 8388608.0);
  }
}

extern "C" void kernel_launch(void* const* d_in, const int* in_sizes, int n_in,
                              void* d_out, int out_size, void* d_ws, size_t ws_size,
                              hipStream_t stream) {
  (void)in_sizes; (void)n_in; (void)out_size; (void)ws_size;
  const float* z = (const float*)d_in[0];
  const float* cb = (const float*)d_in[1];
  float* out = (float*)d_out;
  float* ws = (float*)d_ws;

  float* rn = ws + WS_RN;
  float* en = ws + WS_EN;
  int* idxbuf = (int*)(ws + WS_IDX);
  unsigned int* counts = (unsigned int*)(ws + WS_CNT);
  double* losssum = (double*)(ws + WS_LOSS);

  // Zero the one-hot encodings region (512 MiB) and the small accumulators.
  hipMemsetAsync(out + OFF_ENC, 0, (size_t)N_ROWS * K_CODES * sizeof(float), stream);
  hipMemsetAsync(ws + WS_CNT, 0, K_CODES * sizeof(unsigned int) + 2 * sizeof(double), stream);

  rownorm_k<<<N_ROWS / 256, 256, 0, stream>>>(z, rn);
  enorm_k<<<K_CODES / 256, 256, 0, stream>>>(cb, en);
  argmin_k<<<N_ROWS / BM, 256, 0, stream>>>(z, cb, rn, en, idxbuf, counts, out);
  quant_k<<<512, 256, 0, stream>>>(z, cb, idxbuf, out, losssum);
  final_k<<<1, 256, 0, stream>>>(counts, losssum, out);
}